// Round 12
// baseline (1262.521 us; speedup 1.0000x reference)
//
#include <hip/hip_runtime.h>
#include <hip/hip_bf16.h>
#include <stdint.h>
#include <math.h>

typedef __attribute__((ext_vector_type(4))) float f32x4;
typedef __attribute__((ext_vector_type(8))) __bf16 bf16x8;
typedef __attribute__((ext_vector_type(8))) uint16_t u16x8;
typedef __attribute__((ext_vector_type(4))) uint32_t u32x4;

__device__ __forceinline__ uint16_t f2bf(float f) {
  union { float f; uint32_t u; } v; v.f = f;
  uint32_t r = v.u + 0x7FFFu + ((v.u >> 16) & 1u);
  return (uint16_t)(r >> 16);
}
__device__ __forceinline__ float bf2f(uint16_t b) {
  union { uint32_t u; float f; } v; v.u = ((uint32_t)b) << 16;
  return v.f;
}
__device__ __forceinline__ void gload16(const void* g, void* l) {
  __builtin_amdgcn_global_load_lds(
      (const __attribute__((address_space(1))) uint32_t*)g,
      (__attribute__((address_space(3))) uint32_t*)l, 16, 0, 0);
}

// ---------------------------------------------------------------- converts
__global__ __launch_bounds__(256) void k_conv_x(const float* __restrict__ x,
                                                uint16_t* __restrict__ comb) {
  int i = blockIdx.x * 256 + threadIdx.x;
  int base = i * 8;
  int row = base >> 9;
  int col = base & 511;
  const float* src = x + base;
  f32x4 a = *(const f32x4*)src;
  f32x4 b = *(const f32x4*)(src + 4);
  u16x8 o;
  o[0] = f2bf(a[0]); o[1] = f2bf(a[1]); o[2] = f2bf(a[2]); o[3] = f2bf(a[3]);
  o[4] = f2bf(b[0]); o[5] = f2bf(b[1]); o[6] = f2bf(b[2]); o[7] = f2bf(b[3]);
  *(u16x8*)(comb + (size_t)row * 576 + col) = o;
}

// tiled transpose: W[K][N] f32 -> WT[N][K] bf16, both sides coalesced
__global__ __launch_bounds__(256) void k_convT(const float* __restrict__ W,
                                               uint16_t* __restrict__ WT,
                                               int K, int N) {
  __shared__ float tile[64][65];
  const int t = threadIdx.x;
  const int n0 = blockIdx.x * 64, k0 = blockIdx.y * 64;
  const int c = t & 63, r0 = t >> 6;
#pragma unroll
  for (int rr = 0; rr < 16; ++rr) {
    int r = r0 * 16 + rr;
    tile[r][c] = W[(size_t)(k0 + r) * N + n0 + c];
  }
  __syncthreads();
#pragma unroll
  for (int rr = 0; rr < 16; ++rr) {
    int r = r0 * 16 + rr;  // output row index within n-tile
    WT[(size_t)(n0 + r) * K + k0 + c] = f2bf(tile[c][r]);
  }
}

__global__ __launch_bounds__(256) void k_conv(const float* __restrict__ W,
                                              uint16_t* __restrict__ O, int n) {
  int i = blockIdx.x * 256 + threadIdx.x;
  if (i < n) O[i] = f2bf(W[i]);
}

// ---------------------------------------------------------------- encoder
// f32 OpenBLAS-replica accumulation (bit-exact, PASSING since R10):
// one accumulator per element, k ascending, kc-panel joins at 384.
// R12 change: T14 async-STAGE (prefetch next tile to regs during compute).
// Staging order only — arithmetic untouched.
template <int K, bool RELU>
__global__ __launch_bounds__(256)
void k_enc(const float* __restrict__ A, const float* __restrict__ W,
           const float* __restrict__ bias, float* __restrict__ C, int N) {
  __shared__ __align__(16) float xs[64][136];  // [k][m], padded
  __shared__ __align__(16) float ws[64][68];   // [k][n], padded
  const int t = threadIdx.x;
  const int m0 = blockIdx.y * 128, n0 = blockIdx.x * 64;
  const int mg = t >> 4, ng = t & 15;

  float res[8][4], acc[8][4];
#pragma unroll
  for (int i = 0; i < 8; ++i)
#pragma unroll
    for (int j = 0; j < 4; ++j) { res[i][j] = 0.f; acc[i][j] = 0.f; }

  const int xr = t >> 1, xk = (t & 1) * 32;
  const int wrr = t >> 2, wj = (t & 3) * 16;

  f32x4 pa[8], pb[4];
  const float* Arow = A + (size_t)(m0 + xr) * K + xk;
  const float* Wrow = W + (size_t)wrr * N + n0 + wj;

  // prologue: prefetch tile 0
#pragma unroll
  for (int u = 0; u < 8; ++u) pa[u] = *(const f32x4*)(Arow + u * 4);
#pragma unroll
  for (int u = 0; u < 4; ++u) pb[u] = *(const f32x4*)(Wrow + u * 4);

  constexpr int NT = K / 64;
  for (int c = 0; c < NT; ++c) {
    const int k0 = c * 64;
    __syncthreads();  // prev compute done -> safe to overwrite LDS
#pragma unroll
    for (int u = 0; u < 8; ++u) {
      xs[xk + u * 4 + 0][xr] = pa[u][0];
      xs[xk + u * 4 + 1][xr] = pa[u][1];
      xs[xk + u * 4 + 2][xr] = pa[u][2];
      xs[xk + u * 4 + 3][xr] = pa[u][3];
    }
#pragma unroll
    for (int u = 0; u < 4; ++u) *(f32x4*)&ws[wrr][wj + u * 4] = pb[u];
    __syncthreads();
    if (c + 1 < NT) {  // issue next-tile loads; land under compute
      const float* An = Arow + (c + 1) * 64;
      const float* Wn = W + (size_t)((c + 1) * 64 + wrr) * N + n0 + wj;
#pragma unroll
      for (int u = 0; u < 8; ++u) pa[u] = *(const f32x4*)(An + u * 4);
#pragma unroll
      for (int u = 0; u < 4; ++u) pb[u] = *(const f32x4*)(Wn + u * 4);
    }
    if (k0 > 0 && (k0 % 384) == 0) {  // OpenBLAS kc-panel boundary (Q=384)
#pragma unroll
      for (int i = 0; i < 8; ++i)
#pragma unroll
        for (int j = 0; j < 4; ++j) { res[i][j] += acc[i][j]; acc[i][j] = 0.f; }
    }
#pragma unroll
    for (int k = 0; k < 64; ++k) {
      f32x4 x0 = *(const f32x4*)&xs[k][mg * 8];
      f32x4 x1 = *(const f32x4*)&xs[k][mg * 8 + 4];
      f32x4 wv = *(const f32x4*)&ws[k][ng * 4];
#pragma unroll
      for (int j = 0; j < 4; ++j) {
        acc[0][j] = fmaf(x0[0], wv[j], acc[0][j]);
        acc[1][j] = fmaf(x0[1], wv[j], acc[1][j]);
        acc[2][j] = fmaf(x0[2], wv[j], acc[2][j]);
        acc[3][j] = fmaf(x0[3], wv[j], acc[3][j]);
        acc[4][j] = fmaf(x1[0], wv[j], acc[4][j]);
        acc[5][j] = fmaf(x1[1], wv[j], acc[5][j]);
        acc[6][j] = fmaf(x1[2], wv[j], acc[6][j]);
        acc[7][j] = fmaf(x1[3], wv[j], acc[7][j]);
      }
    }
  }
#pragma unroll
  for (int i = 0; i < 8; ++i)
#pragma unroll
    for (int j = 0; j < 4; ++j) res[i][j] += acc[i][j];  // final panel join

#pragma unroll
  for (int i = 0; i < 8; ++i) {
    f32x4 o;
#pragma unroll
    for (int j = 0; j < 4; ++j) {
      float v = res[i][j] + bias[n0 + ng * 4 + j];
      if (RELU) v = fmaxf(v, 0.f);
      o[j] = v;
    }
    *(f32x4*)(C + (size_t)(m0 + mg * 8 + i) * N + n0 + ng * 4) = o;
  }
}

// ---------------------------------------------------------------- Hopfield
// PASSING arithmetic (R10): f32 state, numpy pairwise-8 tree, tie -> -1.
// 8-lanes-per-sample; shfl_xor reduce == numpy tree bitwise.
#define KNIFE_TAU 1e-6f

__device__ __forceinline__ void retrieve8(float (&s)[8],
                                          const float (*w)[64], int l) {
  for (int it = 0; it < 10; ++it) {
    bool changed = false;
#pragma unroll
    for (int i = 0; i < 64; ++i) {
      float r = 0.f;
#pragma unroll
      for (int c = 0; c < 8; ++c)
        r = fmaf(s[c], w[i][8 * c + l], r);
      r += __shfl_xor(r, 1);
      r += __shfl_xor(r, 2);
      r += __shfl_xor(r, 4);
      float ns = r > 0.f ? 1.f : -1.f;   // np: where(act > 0, 1, -1)
      bool own = ((i & 7) == l);
      float cur = s[i >> 3];
      float nv = own ? ns : cur;          // only owner lane updates
      changed |= (nv != cur);
      s[i >> 3] = nv;
    }
    if (!__any(changed)) break;  // fixed point: further sweeps are identity
  }
}

__device__ __forceinline__ uint64_t gather_mask(const float (&s)[8], int g) {
  uint64_t m = 0;
#pragma unroll
  for (int c = 0; c < 8; ++c) {
    unsigned long long b = __ballot(s[c] > 0.f);
    m |= (uint64_t)((b >> (g * 8)) & 0xFFull) << (8 * c);
  }
  return m;
}

__global__ __launch_bounds__(256) void k_hopfield(const float* __restrict__ enc,
                                                  const float* __restrict__ hw,
                                                  uint16_t* __restrict__ comb) {
  __shared__ __align__(16) float w[64][64];
  const int t = threadIdx.x;
#pragma unroll
  for (int i = 0; i < 4; ++i)
    ((f32x4*)&w[0][0])[t * 4 + i] = ((const f32x4*)hw)[t * 4 + i];
  __syncthreads();

  const int lane = t & 63, wv = t >> 6;
  const int g = lane >> 3, l = lane & 7;
  const int sid = (blockIdx.x * 4 + wv) * 8 + g;
  const float* er = enc + (size_t)sid * 64;

  uint32_t imask = 0;
  int kc = -1;
  bool kpos = false;
#pragma unroll
  for (int c = 0; c < 8; ++c) {
    float v = er[8 * c + l];
    if (v > 0.f) imask |= (1u << c);
    if (kc < 0 && fabsf(v) < KNIFE_TAU) { kc = c; kpos = v > 0.f; }
  }
  unsigned long long kb = __ballot(kc >= 0);
  uint32_t gbits = (uint32_t)((kb >> (g * 8)) & 0xFFull);
  bool hasknife = gbits != 0;
  int klane = g * 8 + (__ffs(gbits) - 1);  // valid only if hasknife
  bool is_kl = hasknife && (lane == klane);
  uint32_t kbit = (kc >= 0) ? (1u << (kc & 7)) : 0u;

  uint32_t ma_bits = is_kl ? (imask | kbit) : imask;
  float sA[8];
#pragma unroll
  for (int c = 0; c < 8; ++c) sA[c] = ((ma_bits >> c) & 1u) ? 1.f : -1.f;
  retrieve8(sA, w, l);
  uint64_t mA = gather_mask(sA, g);
  uint64_t m = mA;

  if (__any(hasknife)) {
    if (hasknife) {
      uint32_t mb_bits = is_kl ? (imask & ~kbit) : imask;
      float sB[8];
#pragma unroll
      for (int c = 0; c < 8; ++c) sB[c] = ((mb_bits >> c) & 1u) ? 1.f : -1.f;
      retrieve8(sB, w, l);
      uint64_t mB = gather_mask(sB, g);
      if (mA != mB) {
        int kp = __shfl(kpos ? 1 : 0, klane);
        m = kp ? mA : mB;
      }
    }
  }

  uint32_t byte = (uint32_t)((m >> (8 * l)) & 0xFFull);
  u32x4 o;
#pragma unroll
  for (int p = 0; p < 4; ++p) {
    uint32_t lo = ((byte >> (2 * p)) & 1u) ? 0x3F80u : 0u;
    uint32_t hi = ((byte >> (2 * p + 1)) & 1u) ? 0x3F800000u : 0u;
    o[p] = lo | hi;
  }
  *(u32x4*)(comb + (size_t)sid * 576 + 512 + l * 8) = o;
}

// ---------------------------------------------------------------- bf16 MFMA GEMM
// R12 change: staging via global_load_lds width=16 (m97 pattern).
// idx = pass*256 + t; LDS byte offset = idx*16 (lane-linear, satisfies the
// wave-uniform-base + lane*16 HW constraint); src row = idx>>2, col8 = idx&3.
__global__ __launch_bounds__(256)
void k_gemm_bf16(const uint16_t* __restrict__ A, const uint16_t* __restrict__ BT,
                 const float* __restrict__ bias, uint16_t* __restrict__ C,
                 int M, int N, int K, int relu) {
  constexpr int BM = 128, BN = 128, BK = 32;
  __shared__ __align__(16) uint16_t As[BM][BK];
  __shared__ __align__(16) uint16_t Bs[BN][BK];
  const int t = threadIdx.x;
  const int lane = t & 63, wid = t >> 6;
  const int wr = wid >> 1, wc = wid & 1;
  const int bm = blockIdx.y * BM, bn = blockIdx.x * BN;

  f32x4 acc[4][4] = {};

  const int l15 = lane & 15, kb = (lane >> 4) * 8;
  // staging indices (2 passes of 256 threads each, A and B)
  const int i0 = t, i1 = t + 256;
  const int r0 = i0 >> 2, c0 = (i0 & 3) * 8;
  const int r1 = i1 >> 2, c1 = (i1 & 3) * 8;
  const uint16_t* A0 = A + (size_t)(bm + r0) * K + c0;
  const uint16_t* A1 = A + (size_t)(bm + r1) * K + c1;
  const uint16_t* B0 = BT + (size_t)(bn + r0) * K + c0;
  const uint16_t* B1 = BT + (size_t)(bn + r1) * K + c1;
  uint16_t* Al = &As[0][0];
  uint16_t* Bl = &Bs[0][0];

  for (int kt = 0; kt < K / BK; ++kt) {
    __syncthreads();
    const int ko = kt * BK;
    gload16(A0 + ko, Al + i0 * 8);
    gload16(A1 + ko, Al + i1 * 8);
    gload16(B0 + ko, Bl + i0 * 8);
    gload16(B1 + ko, Bl + i1 * 8);
    __syncthreads();  // drains vmcnt -> LDS tiles ready
    bf16x8 af[4], bf[4];
#pragma unroll
    for (int m = 0; m < 4; ++m)
      af[m] = *(const bf16x8*)&As[wr * 64 + m * 16 + l15][kb];
#pragma unroll
    for (int n = 0; n < 4; ++n)
      bf[n] = *(const bf16x8*)&Bs[wc * 64 + n * 16 + l15][kb];
#pragma unroll
    for (int m = 0; m < 4; ++m)
#pragma unroll
      for (int n = 0; n < 4; ++n)
        acc[m][n] = __builtin_amdgcn_mfma_f32_16x16x32_bf16(af[m], bf[n],
                                                            acc[m][n], 0, 0, 0);
  }
#pragma unroll
  for (int m = 0; m < 4; ++m) {
    int row = bm + wr * 64 + m * 16 + (lane >> 4) * 4;
#pragma unroll
    for (int n = 0; n < 4; ++n) {
      int col = bn + wc * 64 + n * 16 + l15;
      float bsv = bias[col];
#pragma unroll
      for (int r = 0; r < 4; ++r) {
        float v = acc[m][n][r] + bsv;
        if (relu) v = fmaxf(v, 0.f);
        C[(size_t)(row + r) * N + col] = f2bf(v);
      }
    }
  }
}

// ---------------------------------------------------------------- n3 (N=2)
__global__ __launch_bounds__(256) void k_n3(const uint16_t* __restrict__ h2,
                                            const uint16_t* __restrict__ w3,
                                            const float* __restrict__ b3,
                                            float* __restrict__ out, int M) {
  const int lane = threadIdx.x & 63;
  const int wglob = (blockIdx.x * 256 + threadIdx.x) >> 6;
  const int nw = (gridDim.x * 256) >> 6;
  u16x8 wa = *(const u16x8*)(w3 + lane * 16);
  u16x8 wb = *(const u16x8*)(w3 + lane * 16 + 8);
  u16x8 wc = *(const u16x8*)(w3 + 1024 + lane * 16);
  u16x8 wd = *(const u16x8*)(w3 + 1024 + lane * 16 + 8);
  const float b0 = b3[0], b1 = b3[1];
  for (int row = wglob; row < M; row += nw) {
    const uint16_t* hr = h2 + (size_t)row * 1024;
    u16x8 h0 = *(const u16x8*)(hr + lane * 8);
    u16x8 h1 = *(const u16x8*)(hr + 512 + lane * 8);
    float a0 = 0.f, a1 = 0.f;
#pragma unroll
    for (int e = 0; e < 4; ++e) {
      float h = bf2f(h0[e]);
      a0 = fmaf(h, bf2f(wa[2 * e]), a0);
      a1 = fmaf(h, bf2f(wa[2 * e + 1]), a1);
    }
#pragma unroll
    for (int e = 4; e < 8; ++e) {
      float h = bf2f(h0[e]);
      a0 = fmaf(h, bf2f(wb[2 * e - 8]), a0);
      a1 = fmaf(h, bf2f(wb[2 * e - 7]), a1);
    }
#pragma unroll
    for (int e = 0; e < 4; ++e) {
      float h = bf2f(h1[e]);
      a0 = fmaf(h, bf2f(wc[2 * e]), a0);
      a1 = fmaf(h, bf2f(wc[2 * e + 1]), a1);
    }
#pragma unroll
    for (int e = 4; e < 8; ++e) {
      float h = bf2f(h1[e]);
      a0 = fmaf(h, bf2f(wd[2 * e - 8]), a0);
      a1 = fmaf(h, bf2f(wd[2 * e - 7]), a1);
    }
#pragma unroll
    for (int off = 32; off; off >>= 1) {
      a0 += __shfl_xor(a0, off, 64);
      a1 += __shfl_xor(a1, off, 64);
    }
    if (lane == 0) {
      out[(size_t)row * 2 + 0] = a0 + b0;
      out[(size_t)row * 2 + 1] = a1 + b1;
    }
  }
}

// ---------------------------------------------------------------- launch
extern "C" void kernel_launch(void* const* d_in, const int* in_sizes, int n_in,
                              void* d_out, int out_size, void* d_ws, size_t ws_size,
                              hipStream_t stream) {
  const float* x     = (const float*)d_in[0];
  const float* e_w1  = (const float*)d_in[1];
  const float* e_b1  = (const float*)d_in[2];
  const float* e_w2  = (const float*)d_in[3];
  const float* e_b2  = (const float*)d_in[4];
  const float* hop_w = (const float*)d_in[5];
  const float* n_w1  = (const float*)d_in[6];
  const float* n_b1  = (const float*)d_in[7];
  const float* n_w2  = (const float*)d_in[8];
  const float* n_b2  = (const float*)d_in[9];
  const float* n_w3  = (const float*)d_in[10];
  const float* n_b3  = (const float*)d_in[11];
  float* out = (float*)d_out;
  char* ws = (char*)d_ws;

  float*    h1e  = (float*)(ws + 0);              // 32768x1024 f32 (phase A)
  uint16_t* h1   = (uint16_t*)(ws + 0);           // 32768x1024 bf16 (phase C)
  uint16_t* h2   = (uint16_t*)(ws + 67108864);
  uint16_t* comb = (uint16_t*)(ws + 134217728);
  float*    enc  = (float*)(ws + 171966464);
  uint16_t* w1t  = (uint16_t*)(ws + 180355072);
  uint16_t* w2t  = (uint16_t*)(ws + 181534720);
  uint16_t* w3b  = (uint16_t*)(ws + 183631872);

  k_conv_x<<<8192, 256, 0, stream>>>(x, comb);
  k_convT<<<dim3(1024 / 64, 576 / 64), 256, 0, stream>>>(n_w1, w1t, 576, 1024);
  k_convT<<<dim3(1024 / 64, 1024 / 64), 256, 0, stream>>>(n_w2, w2t, 1024, 1024);
  k_conv<<<(2048 + 255) / 256, 256, 0, stream>>>(n_w3, w3b, 2048);

  // encoder — f32 OpenBLAS replica + T14 async staging
  k_enc<512, true><<<dim3(1024 / 64, 32768 / 128), 256, 0, stream>>>(
      x, e_w1, e_b1, h1e, 1024);
  k_enc<1024, false><<<dim3(1, 32768 / 128), 256, 0, stream>>>(
      h1e, e_w2, e_b2, enc, 64);

  // hopfield — 8-lane/sample, numpy pairwise tree
  k_hopfield<<<32768 / 32, 256, 0, stream>>>(enc, hop_w, comb);

  // Q-network (bf16 MFMA, global_load_lds staging)
  k_gemm_bf16<<<dim3(1024 / 128, 32768 / 128), 256, 0, stream>>>(
      comb, w1t, n_b1, h1, 32768, 1024, 576, 1);
  k_gemm_bf16<<<dim3(1024 / 128, 32768 / 128), 256, 0, stream>>>(
      h1, w2t, n_b2, h2, 32768, 1024, 1024, 1);
  k_n3<<<512, 256, 0, stream>>>(h2, w3b, n_b3, out, 32768);
}

// Round 13
// 1127.588 us; speedup vs baseline: 1.1197x; 1.1197x over previous
//
#include <hip/hip_runtime.h>
#include <hip/hip_bf16.h>
#include <stdint.h>
#include <math.h>

typedef __attribute__((ext_vector_type(4))) float f32x4;
typedef __attribute__((ext_vector_type(8))) __bf16 bf16x8;
typedef __attribute__((ext_vector_type(8))) uint16_t u16x8;
typedef __attribute__((ext_vector_type(4))) uint32_t u32x4;

__device__ __forceinline__ uint16_t f2bf(float f) {
  union { float f; uint32_t u; } v; v.f = f;
  uint32_t r = v.u + 0x7FFFu + ((v.u >> 16) & 1u);
  return (uint16_t)(r >> 16);
}
__device__ __forceinline__ float bf2f(uint16_t b) {
  union { uint32_t u; float f; } v; v.u = ((uint32_t)b) << 16;
  return v.f;
}
__device__ __forceinline__ void gload16(const void* g, void* l) {
  __builtin_amdgcn_global_load_lds(
      (const __attribute__((address_space(1))) uint32_t*)g,
      (__attribute__((address_space(3))) uint32_t*)l, 16, 0, 0);
}

// ---------------------------------------------------------------- converts
__global__ __launch_bounds__(256) void k_conv_x(const float* __restrict__ x,
                                                uint16_t* __restrict__ comb) {
  int i = blockIdx.x * 256 + threadIdx.x;
  int base = i * 8;
  int row = base >> 9;
  int col = base & 511;
  const float* src = x + base;
  f32x4 a = *(const f32x4*)src;
  f32x4 b = *(const f32x4*)(src + 4);
  u16x8 o;
  o[0] = f2bf(a[0]); o[1] = f2bf(a[1]); o[2] = f2bf(a[2]); o[3] = f2bf(a[3]);
  o[4] = f2bf(b[0]); o[5] = f2bf(b[1]); o[6] = f2bf(b[2]); o[7] = f2bf(b[3]);
  *(u16x8*)(comb + (size_t)row * 576 + col) = o;
}

// tiled transpose: W[K][N] f32 -> WT[N][K] bf16, both sides coalesced
__global__ __launch_bounds__(256) void k_convT(const float* __restrict__ W,
                                               uint16_t* __restrict__ WT,
                                               int K, int N) {
  __shared__ float tile[64][65];
  const int t = threadIdx.x;
  const int n0 = blockIdx.x * 64, k0 = blockIdx.y * 64;
  const int c = t & 63, r0 = t >> 6;
#pragma unroll
  for (int rr = 0; rr < 16; ++rr) {
    int r = r0 * 16 + rr;
    tile[r][c] = W[(size_t)(k0 + r) * N + n0 + c];
  }
  __syncthreads();
#pragma unroll
  for (int rr = 0; rr < 16; ++rr) {
    int r = r0 * 16 + rr;
    WT[(size_t)(n0 + r) * K + k0 + c] = f2bf(tile[c][r]);
  }
}

__global__ __launch_bounds__(256) void k_conv(const float* __restrict__ W,
                                              uint16_t* __restrict__ O, int n) {
  int i = blockIdx.x * 256 + threadIdx.x;
  if (i < n) O[i] = f2bf(W[i]);
}

// ---------------------------------------------------------------- encoder
// f32 OpenBLAS-replica accumulation (bit-exact, PASSING since R10): one f32
// accumulator per element, k ascending, kc-panel joins at multiples of 384.
// R13: K-tile 32, LDS 24.6KB (xs unpadded — writes lane-contiguous, reads
// broadcast), __launch_bounds__(256,4): 4 blocks/CU (was 3), VGPR<=128.
// R12's reg-prefetch reverted (crossed the 128-VGPR cliff: occ 22->11.6%).
template <int K, bool RELU>
__global__ __launch_bounds__(256, 4)
void k_enc(const float* __restrict__ A, const float* __restrict__ W,
           const float* __restrict__ bias, float* __restrict__ C, int N) {
  __shared__ __align__(16) float xs[32][128];  // [k][m]
  __shared__ __align__(16) float ws[32][68];   // [k][n], +4 pad (write banks)
  const int t = threadIdx.x;
  const int m0 = blockIdx.y * 128, n0 = blockIdx.x * 64;
  const int mg = t >> 4, ng = t & 15;

  float res[8][4], acc[8][4];
#pragma unroll
  for (int i = 0; i < 8; ++i)
#pragma unroll
    for (int j = 0; j < 4; ++j) { res[i][j] = 0.f; acc[i][j] = 0.f; }

  const int xr = t >> 1, xk = (t & 1) * 16;
  const int wrr = t >> 3, wj = (t & 7) * 8;

  for (int c = 0; c < K / 32; ++c) {
    const int k0 = c * 32;
    if (k0 > 0 && (k0 % 384) == 0) {  // OpenBLAS kc-panel boundary (Q=384)
#pragma unroll
      for (int i = 0; i < 8; ++i)
#pragma unroll
        for (int j = 0; j < 4; ++j) { res[i][j] += acc[i][j]; acc[i][j] = 0.f; }
    }
    __syncthreads();
#pragma unroll
    for (int u = 0; u < 4; ++u) {
      f32x4 v = *(const f32x4*)(A + (size_t)(m0 + xr) * K + k0 + xk + u * 4);
      xs[xk + u * 4 + 0][xr] = v[0];
      xs[xk + u * 4 + 1][xr] = v[1];
      xs[xk + u * 4 + 2][xr] = v[2];
      xs[xk + u * 4 + 3][xr] = v[3];
    }
#pragma unroll
    for (int u = 0; u < 2; ++u)
      *(f32x4*)&ws[wrr][wj + u * 4] =
          *(const f32x4*)(W + (size_t)(k0 + wrr) * N + n0 + wj + u * 4);
    __syncthreads();
#pragma unroll
    for (int k = 0; k < 32; ++k) {
      f32x4 x0 = *(const f32x4*)&xs[k][mg * 8];
      f32x4 x1 = *(const f32x4*)&xs[k][mg * 8 + 4];
      f32x4 wv = *(const f32x4*)&ws[k][ng * 4];
#pragma unroll
      for (int j = 0; j < 4; ++j) {
        acc[0][j] = fmaf(x0[0], wv[j], acc[0][j]);
        acc[1][j] = fmaf(x0[1], wv[j], acc[1][j]);
        acc[2][j] = fmaf(x0[2], wv[j], acc[2][j]);
        acc[3][j] = fmaf(x0[3], wv[j], acc[3][j]);
        acc[4][j] = fmaf(x1[0], wv[j], acc[4][j]);
        acc[5][j] = fmaf(x1[1], wv[j], acc[5][j]);
        acc[6][j] = fmaf(x1[2], wv[j], acc[6][j]);
        acc[7][j] = fmaf(x1[3], wv[j], acc[7][j]);
      }
    }
  }
#pragma unroll
  for (int i = 0; i < 8; ++i)
#pragma unroll
    for (int j = 0; j < 4; ++j) res[i][j] += acc[i][j];  // final panel join

#pragma unroll
  for (int i = 0; i < 8; ++i) {
    f32x4 o;
#pragma unroll
    for (int j = 0; j < 4; ++j) {
      float v = res[i][j] + bias[n0 + ng * 4 + j];
      if (RELU) v = fmaxf(v, 0.f);
      o[j] = v;
    }
    *(f32x4*)(C + (size_t)(m0 + mg * 8 + i) * N + n0 + ng * 4) = o;
  }
}

// ---------------------------------------------------------------- Hopfield
// PASSING arithmetic (R10): f32 state, numpy pairwise-8 tree, tie -> -1.
// 8-lanes-per-sample; shfl_xor reduce == numpy tree bitwise.
#define KNIFE_TAU 1e-6f

__device__ __forceinline__ void retrieve8(float (&s)[8],
                                          const float (*w)[64], int l) {
  for (int it = 0; it < 10; ++it) {
    bool changed = false;
#pragma unroll
    for (int i = 0; i < 64; ++i) {
      float r = 0.f;
#pragma unroll
      for (int c = 0; c < 8; ++c)
        r = fmaf(s[c], w[i][8 * c + l], r);
      r += __shfl_xor(r, 1);
      r += __shfl_xor(r, 2);
      r += __shfl_xor(r, 4);
      float ns = r > 0.f ? 1.f : -1.f;   // np: where(act > 0, 1, -1)
      bool own = ((i & 7) == l);
      float cur = s[i >> 3];
      float nv = own ? ns : cur;
      changed |= (nv != cur);
      s[i >> 3] = nv;
    }
    if (!__any(changed)) break;
  }
}

__device__ __forceinline__ uint64_t gather_mask(const float (&s)[8], int g) {
  uint64_t m = 0;
#pragma unroll
  for (int c = 0; c < 8; ++c) {
    unsigned long long b = __ballot(s[c] > 0.f);
    m |= (uint64_t)((b >> (g * 8)) & 0xFFull) << (8 * c);
  }
  return m;
}

__global__ __launch_bounds__(256) void k_hopfield(const float* __restrict__ enc,
                                                  const float* __restrict__ hw,
                                                  uint16_t* __restrict__ comb) {
  __shared__ __align__(16) float w[64][64];
  const int t = threadIdx.x;
#pragma unroll
  for (int i = 0; i < 4; ++i)
    ((f32x4*)&w[0][0])[t * 4 + i] = ((const f32x4*)hw)[t * 4 + i];
  __syncthreads();

  const int lane = t & 63, wv = t >> 6;
  const int g = lane >> 3, l = lane & 7;
  const int sid = (blockIdx.x * 4 + wv) * 8 + g;
  const float* er = enc + (size_t)sid * 64;

  uint32_t imask = 0;
  int kc = -1;
  bool kpos = false;
#pragma unroll
  for (int c = 0; c < 8; ++c) {
    float v = er[8 * c + l];
    if (v > 0.f) imask |= (1u << c);
    if (kc < 0 && fabsf(v) < KNIFE_TAU) { kc = c; kpos = v > 0.f; }
  }
  unsigned long long kb = __ballot(kc >= 0);
  uint32_t gbits = (uint32_t)((kb >> (g * 8)) & 0xFFull);
  bool hasknife = gbits != 0;
  int klane = g * 8 + (__ffs(gbits) - 1);
  bool is_kl = hasknife && (lane == klane);
  uint32_t kbit = (kc >= 0) ? (1u << (kc & 7)) : 0u;

  uint32_t ma_bits = is_kl ? (imask | kbit) : imask;
  float sA[8];
#pragma unroll
  for (int c = 0; c < 8; ++c) sA[c] = ((ma_bits >> c) & 1u) ? 1.f : -1.f;
  retrieve8(sA, w, l);
  uint64_t mA = gather_mask(sA, g);
  uint64_t m = mA;

  if (__any(hasknife)) {
    if (hasknife) {
      uint32_t mb_bits = is_kl ? (imask & ~kbit) : imask;
      float sB[8];
#pragma unroll
      for (int c = 0; c < 8; ++c) sB[c] = ((mb_bits >> c) & 1u) ? 1.f : -1.f;
      retrieve8(sB, w, l);
      uint64_t mB = gather_mask(sB, g);
      if (mA != mB) {
        int kp = __shfl(kpos ? 1 : 0, klane);
        m = kp ? mA : mB;
      }
    }
  }

  uint32_t byte = (uint32_t)((m >> (8 * l)) & 0xFFull);
  u32x4 o;
#pragma unroll
  for (int p = 0; p < 4; ++p) {
    uint32_t lo = ((byte >> (2 * p)) & 1u) ? 0x3F80u : 0u;
    uint32_t hi = ((byte >> (2 * p + 1)) & 1u) ? 0x3F800000u : 0u;
    o[p] = lo | hi;
  }
  *(u32x4*)(comb + (size_t)sid * 576 + 512 + l * 8) = o;
}

// ---------------------------------------------------------------- bf16 MFMA GEMM
// global_load_lds width-16 staging (R12, kept: part of the −59µs net win).
__global__ __launch_bounds__(256)
void k_gemm_bf16(const uint16_t* __restrict__ A, const uint16_t* __restrict__ BT,
                 const float* __restrict__ bias, uint16_t* __restrict__ C,
                 int M, int N, int K, int relu) {
  constexpr int BM = 128, BN = 128, BK = 32;
  __shared__ __align__(16) uint16_t As[BM][BK];
  __shared__ __align__(16) uint16_t Bs[BN][BK];
  const int t = threadIdx.x;
  const int lane = t & 63, wid = t >> 6;
  const int wr = wid >> 1, wc = wid & 1;
  const int bm = blockIdx.y * BM, bn = blockIdx.x * BN;

  f32x4 acc[4][4] = {};

  const int l15 = lane & 15, kb = (lane >> 4) * 8;
  const int i0 = t, i1 = t + 256;
  const int r0 = i0 >> 2, c0 = (i0 & 3) * 8;
  const int r1 = i1 >> 2, c1 = (i1 & 3) * 8;
  const uint16_t* A0 = A + (size_t)(bm + r0) * K + c0;
  const uint16_t* A1 = A + (size_t)(bm + r1) * K + c1;
  const uint16_t* B0 = BT + (size_t)(bn + r0) * K + c0;
  const uint16_t* B1 = BT + (size_t)(bn + r1) * K + c1;
  uint16_t* Al = &As[0][0];
  uint16_t* Bl = &Bs[0][0];

  for (int kt = 0; kt < K / BK; ++kt) {
    __syncthreads();
    const int ko = kt * BK;
    gload16(A0 + ko, Al + i0 * 8);
    gload16(A1 + ko, Al + i1 * 8);
    gload16(B0 + ko, Bl + i0 * 8);
    gload16(B1 + ko, Bl + i1 * 8);
    __syncthreads();
    bf16x8 af[4], bf[4];
#pragma unroll
    for (int m = 0; m < 4; ++m)
      af[m] = *(const bf16x8*)&As[wr * 64 + m * 16 + l15][kb];
#pragma unroll
    for (int n = 0; n < 4; ++n)
      bf[n] = *(const bf16x8*)&Bs[wc * 64 + n * 16 + l15][kb];
#pragma unroll
    for (int m = 0; m < 4; ++m)
#pragma unroll
      for (int n = 0; n < 4; ++n)
        acc[m][n] = __builtin_amdgcn_mfma_f32_16x16x32_bf16(af[m], bf[n],
                                                            acc[m][n], 0, 0, 0);
  }
#pragma unroll
  for (int m = 0; m < 4; ++m) {
    int row = bm + wr * 64 + m * 16 + (lane >> 4) * 4;
#pragma unroll
    for (int n = 0; n < 4; ++n) {
      int col = bn + wc * 64 + n * 16 + l15;
      float bsv = bias[col];
#pragma unroll
      for (int r = 0; r < 4; ++r) {
        float v = acc[m][n][r] + bsv;
        if (relu) v = fmaxf(v, 0.f);
        C[(size_t)(row + r) * N + col] = f2bf(v);
      }
    }
  }
}

// ---------------------------------------------------------------- n3 (N=2)
__global__ __launch_bounds__(256) void k_n3(const uint16_t* __restrict__ h2,
                                            const uint16_t* __restrict__ w3,
                                            const float* __restrict__ b3,
                                            float* __restrict__ out, int M) {
  const int lane = threadIdx.x & 63;
  const int wglob = (blockIdx.x * 256 + threadIdx.x) >> 6;
  const int nw = (gridDim.x * 256) >> 6;
  u16x8 wa = *(const u16x8*)(w3 + lane * 16);
  u16x8 wb = *(const u16x8*)(w3 + lane * 16 + 8);
  u16x8 wc = *(const u16x8*)(w3 + 1024 + lane * 16);
  u16x8 wd = *(const u16x8*)(w3 + 1024 + lane * 16 + 8);
  const float b0 = b3[0], b1 = b3[1];
  for (int row = wglob; row < M; row += nw) {
    const uint16_t* hr = h2 + (size_t)row * 1024;
    u16x8 h0 = *(const u16x8*)(hr + lane * 8);
    u16x8 h1 = *(const u16x8*)(hr + 512 + lane * 8);
    float a0 = 0.f, a1 = 0.f;
#pragma unroll
    for (int e = 0; e < 4; ++e) {
      float h = bf2f(h0[e]);
      a0 = fmaf(h, bf2f(wa[2 * e]), a0);
      a1 = fmaf(h, bf2f(wa[2 * e + 1]), a1);
    }
#pragma unroll
    for (int e = 4; e < 8; ++e) {
      float h = bf2f(h0[e]);
      a0 = fmaf(h, bf2f(wb[2 * e - 8]), a0);
      a1 = fmaf(h, bf2f(wb[2 * e - 7]), a1);
    }
#pragma unroll
    for (int e = 0; e < 4; ++e) {
      float h = bf2f(h1[e]);
      a0 = fmaf(h, bf2f(wc[2 * e]), a0);
      a1 = fmaf(h, bf2f(wc[2 * e + 1]), a1);
    }
#pragma unroll
    for (int e = 4; e < 8; ++e) {
      float h = bf2f(h1[e]);
      a0 = fmaf(h, bf2f(wd[2 * e - 8]), a0);
      a1 = fmaf(h, bf2f(wd[2 * e - 7]), a1);
    }
#pragma unroll
    for (int off = 32; off; off >>= 1) {
      a0 += __shfl_xor(a0, off, 64);
      a1 += __shfl_xor(a1, off, 64);
    }
    if (lane == 0) {
      out[(size_t)row * 2 + 0] = a0 + b0;
      out[(size_t)row * 2 + 1] = a1 + b1;
    }
  }
}

// ---------------------------------------------------------------- launch
extern "C" void kernel_launch(void* const* d_in, const int* in_sizes, int n_in,
                              void* d_out, int out_size, void* d_ws, size_t ws_size,
                              hipStream_t stream) {
  const float* x     = (const float*)d_in[0];
  const float* e_w1  = (const float*)d_in[1];
  const float* e_b1  = (const float*)d_in[2];
  const float* e_w2  = (const float*)d_in[3];
  const float* e_b2  = (const float*)d_in[4];
  const float* hop_w = (const float*)d_in[5];
  const float* n_w1  = (const float*)d_in[6];
  const float* n_b1  = (const float*)d_in[7];
  const float* n_w2  = (const float*)d_in[8];
  const float* n_b2  = (const float*)d_in[9];
  const float* n_w3  = (const float*)d_in[10];
  const float* n_b3  = (const float*)d_in[11];
  float* out = (float*)d_out;
  char* ws = (char*)d_ws;

  float*    h1e  = (float*)(ws + 0);              // 32768x1024 f32 (phase A)
  uint16_t* h1   = (uint16_t*)(ws + 0);           // 32768x1024 bf16 (phase C)
  uint16_t* h2   = (uint16_t*)(ws + 67108864);
  uint16_t* comb = (uint16_t*)(ws + 134217728);
  float*    enc  = (float*)(ws + 171966464);
  uint16_t* w1t  = (uint16_t*)(ws + 180355072);
  uint16_t* w2t  = (uint16_t*)(ws + 181534720);
  uint16_t* w3b  = (uint16_t*)(ws + 183631872);

  k_conv_x<<<8192, 256, 0, stream>>>(x, comb);
  k_convT<<<dim3(1024 / 64, 576 / 64), 256, 0, stream>>>(n_w1, w1t, 576, 1024);
  k_convT<<<dim3(1024 / 64, 1024 / 64), 256, 0, stream>>>(n_w2, w2t, 1024, 1024);
  k_conv<<<(2048 + 255) / 256, 256, 0, stream>>>(n_w3, w3b, 2048);

  // encoder — f32 OpenBLAS replica, K-tile 32, 4 blocks/CU
  k_enc<512, true><<<dim3(1024 / 64, 32768 / 128), 256, 0, stream>>>(
      x, e_w1, e_b1, h1e, 1024);
  k_enc<1024, false><<<dim3(1, 32768 / 128), 256, 0, stream>>>(
      h1e, e_w2, e_b2, enc, 64);

  // hopfield — 8-lane/sample, numpy pairwise tree
  k_hopfield<<<32768 / 32, 256, 0, stream>>>(enc, hop_w, comb);

  // Q-network (bf16 MFMA, global_load_lds staging)
  k_gemm_bf16<<<dim3(1024 / 128, 32768 / 128), 256, 0, stream>>>(
      comb, w1t, n_b1, h1, 32768, 1024, 576, 1);
  k_gemm_bf16<<<dim3(1024 / 128, 32768 / 128), 256, 0, stream>>>(
      h1, w2t, n_b2, h2, 32768, 1024, 1024, 1);
  k_n3<<<512, 256, 0, stream>>>(h2, w3b, n_b3, out, 32768);
}

// Round 14
// 980.394 us; speedup vs baseline: 1.2878x; 1.1501x over previous
//
#include <hip/hip_runtime.h>
#include <hip/hip_bf16.h>
#include <stdint.h>
#include <math.h>

typedef __attribute__((ext_vector_type(4))) float f32x4;
typedef __attribute__((ext_vector_type(8))) __bf16 bf16x8;
typedef __attribute__((ext_vector_type(8))) uint16_t u16x8;
typedef __attribute__((ext_vector_type(4))) uint32_t u32x4;

__device__ __forceinline__ uint16_t f2bf(float f) {
  union { float f; uint32_t u; } v; v.f = f;
  uint32_t r = v.u + 0x7FFFu + ((v.u >> 16) & 1u);
  return (uint16_t)(r >> 16);
}
__device__ __forceinline__ float bf2f(uint16_t b) {
  union { uint32_t u; float f; } v; v.u = ((uint32_t)b) << 16;
  return v.f;
}
__device__ __forceinline__ void gload16(const void* g, void* l) {
  __builtin_amdgcn_global_load_lds(
      (const __attribute__((address_space(1))) uint32_t*)g,
      (__attribute__((address_space(3))) uint32_t*)l, 16, 0, 0);
}

// ---------------------------------------------------------------- converts
__global__ __launch_bounds__(256) void k_conv_x(const float* __restrict__ x,
                                                uint16_t* __restrict__ comb) {
  int i = blockIdx.x * 256 + threadIdx.x;
  int base = i * 8;
  int row = base >> 9;
  int col = base & 511;
  const float* src = x + base;
  f32x4 a = *(const f32x4*)src;
  f32x4 b = *(const f32x4*)(src + 4);
  u16x8 o;
  o[0] = f2bf(a[0]); o[1] = f2bf(a[1]); o[2] = f2bf(a[2]); o[3] = f2bf(a[3]);
  o[4] = f2bf(b[0]); o[5] = f2bf(b[1]); o[6] = f2bf(b[2]); o[7] = f2bf(b[3]);
  *(u16x8*)(comb + (size_t)row * 576 + col) = o;
}

// tiled transpose: W[K][N] f32 -> WT[N][K] bf16, both sides coalesced
__global__ __launch_bounds__(256) void k_convT(const float* __restrict__ W,
                                               uint16_t* __restrict__ WT,
                                               int K, int N) {
  __shared__ float tile[64][65];
  const int t = threadIdx.x;
  const int n0 = blockIdx.x * 64, k0 = blockIdx.y * 64;
  const int c = t & 63, r0 = t >> 6;
#pragma unroll
  for (int rr = 0; rr < 16; ++rr) {
    int r = r0 * 16 + rr;
    tile[r][c] = W[(size_t)(k0 + r) * N + n0 + c];
  }
  __syncthreads();
#pragma unroll
  for (int rr = 0; rr < 16; ++rr) {
    int r = r0 * 16 + rr;
    WT[(size_t)(n0 + r) * K + k0 + c] = f2bf(tile[c][r]);
  }
}

__global__ __launch_bounds__(256) void k_conv(const float* __restrict__ W,
                                              uint16_t* __restrict__ O, int n) {
  int i = blockIdx.x * 256 + threadIdx.x;
  if (i < n) O[i] = f2bf(W[i]);
}

// ---------------------------------------------------------------- encoder
// f32 OpenBLAS-replica accumulation (bit-exact, PASSING since R10).
// R13 structure kept: K-tile 32, 24.6KB LDS, 4 blocks/CU.
template <int K, bool RELU>
__global__ __launch_bounds__(256, 4)
void k_enc(const float* __restrict__ A, const float* __restrict__ W,
           const float* __restrict__ bias, float* __restrict__ C, int N) {
  __shared__ __align__(16) float xs[32][128];  // [k][m]
  __shared__ __align__(16) float ws[32][68];   // [k][n], +4 pad
  const int t = threadIdx.x;
  const int m0 = blockIdx.y * 128, n0 = blockIdx.x * 64;
  const int mg = t >> 4, ng = t & 15;

  float res[8][4], acc[8][4];
#pragma unroll
  for (int i = 0; i < 8; ++i)
#pragma unroll
    for (int j = 0; j < 4; ++j) { res[i][j] = 0.f; acc[i][j] = 0.f; }

  const int xr = t >> 1, xk = (t & 1) * 16;
  const int wrr = t >> 3, wj = (t & 7) * 8;

  for (int c = 0; c < K / 32; ++c) {
    const int k0 = c * 32;
    if (k0 > 0 && (k0 % 384) == 0) {  // OpenBLAS kc-panel boundary (Q=384)
#pragma unroll
      for (int i = 0; i < 8; ++i)
#pragma unroll
        for (int j = 0; j < 4; ++j) { res[i][j] += acc[i][j]; acc[i][j] = 0.f; }
    }
    __syncthreads();
#pragma unroll
    for (int u = 0; u < 4; ++u) {
      f32x4 v = *(const f32x4*)(A + (size_t)(m0 + xr) * K + k0 + xk + u * 4);
      xs[xk + u * 4 + 0][xr] = v[0];
      xs[xk + u * 4 + 1][xr] = v[1];
      xs[xk + u * 4 + 2][xr] = v[2];
      xs[xk + u * 4 + 3][xr] = v[3];
    }
#pragma unroll
    for (int u = 0; u < 2; ++u)
      *(f32x4*)&ws[wrr][wj + u * 4] =
          *(const f32x4*)(W + (size_t)(k0 + wrr) * N + n0 + wj + u * 4);
    __syncthreads();
#pragma unroll
    for (int k = 0; k < 32; ++k) {
      f32x4 x0 = *(const f32x4*)&xs[k][mg * 8];
      f32x4 x1 = *(const f32x4*)&xs[k][mg * 8 + 4];
      f32x4 wv = *(const f32x4*)&ws[k][ng * 4];
#pragma unroll
      for (int j = 0; j < 4; ++j) {
        acc[0][j] = fmaf(x0[0], wv[j], acc[0][j]);
        acc[1][j] = fmaf(x0[1], wv[j], acc[1][j]);
        acc[2][j] = fmaf(x0[2], wv[j], acc[2][j]);
        acc[3][j] = fmaf(x0[3], wv[j], acc[3][j]);
        acc[4][j] = fmaf(x1[0], wv[j], acc[4][j]);
        acc[5][j] = fmaf(x1[1], wv[j], acc[5][j]);
        acc[6][j] = fmaf(x1[2], wv[j], acc[6][j]);
        acc[7][j] = fmaf(x1[3], wv[j], acc[7][j]);
      }
    }
  }
#pragma unroll
  for (int i = 0; i < 8; ++i)
#pragma unroll
    for (int j = 0; j < 4; ++j) res[i][j] += acc[i][j];  // final panel join

#pragma unroll
  for (int i = 0; i < 8; ++i) {
    f32x4 o;
#pragma unroll
    for (int j = 0; j < 4; ++j) {
      float v = res[i][j] + bias[n0 + ng * 4 + j];
      if (RELU) v = fmaxf(v, 0.f);
      o[j] = v;
    }
    *(f32x4*)(C + (size_t)(m0 + mg * 8 + i) * N + n0 + ng * 4) = o;
  }
}

// ---------------------------------------------------------------- Hopfield
// PASSING arithmetic (R10): f32 state, numpy pairwise-8 tree, tie -> -1.
// R14 restructure (perf only, bit-exact): state as an 8-bit mask per lane;
// s_j*w_ij realized as sign-bit XOR (IEEE-exact: (+-1)*w == +-w, and
// fmaf(+-1,w,r) == correctly-rounded r+-w == r + signed_w). Runtime loops
// (no giant unroll) -> no spill; R13 build spilled 50KB/wave (VGPR=256,
// WRITE_SIZE 208MB).
#define KNIFE_TAU 1e-6f

__device__ __forceinline__ uint32_t retrieve_bits(uint32_t sm,
                                                  const float (*w)[64],
                                                  int l) {
  for (int it = 0; it < 10; ++it) {
    bool changed = false;
    for (int i = 0; i < 64; ++i) {  // runtime loop: small body, no spill
      float r = 0.f;
#pragma unroll
      for (int c = 0; c < 8; ++c) {
        float wv = w[i][8 * c + l];
        uint32_t flip = ((~sm >> c) & 1u) << 31;  // bit clear -> s=-1 -> -wv
        r += __uint_as_float(__float_as_uint(wv) ^ flip);
      }
      // == numpy pairwise tree ((r0+r1)+(r2+r3))+((r4+r5)+(r6+r7)) bitwise
      r += __shfl_xor(r, 1);
      r += __shfl_xor(r, 2);
      r += __shfl_xor(r, 4);
      uint32_t nb = r > 0.f ? 1u : 0u;  // np: where(act > 0, 1, -1)
      if ((i & 7) == l) {               // owner lane updates its bit
        uint32_t g = i >> 3;
        uint32_t ob = (sm >> g) & 1u;
        changed |= (nb != ob);
        sm = (sm & ~(1u << g)) | (nb << g);
      }
    }
    if (!__any(changed)) break;  // fixed point: further sweeps are identity
  }
  return sm;
}

__device__ __forceinline__ uint64_t gather_mask_bits(uint32_t sm, int g) {
  uint64_t m = 0;
#pragma unroll
  for (int c = 0; c < 8; ++c) {
    unsigned long long b = __ballot(((sm >> c) & 1u) != 0u);
    m |= (uint64_t)((b >> (g * 8)) & 0xFFull) << (8 * c);
  }
  return m;
}

__global__ __launch_bounds__(256) void k_hopfield(const float* __restrict__ enc,
                                                  const float* __restrict__ hw,
                                                  uint16_t* __restrict__ comb) {
  __shared__ __align__(16) float w[64][64];
  const int t = threadIdx.x;
#pragma unroll
  for (int i = 0; i < 4; ++i)
    ((f32x4*)&w[0][0])[t * 4 + i] = ((const f32x4*)hw)[t * 4 + i];
  __syncthreads();

  const int lane = t & 63, wv = t >> 6;
  const int g = lane >> 3, l = lane & 7;
  const int sid = (blockIdx.x * 4 + wv) * 8 + g;
  const float* er = enc + (size_t)sid * 64;

  uint32_t imask = 0;
  int kc = -1;
  bool kpos = false;
#pragma unroll
  for (int c = 0; c < 8; ++c) {
    float v = er[8 * c + l];
    if (v > 0.f) imask |= (1u << c);
    if (kc < 0 && fabsf(v) < KNIFE_TAU) { kc = c; kpos = v > 0.f; }
  }
  unsigned long long kb = __ballot(kc >= 0);
  uint32_t gbits = (uint32_t)((kb >> (g * 8)) & 0xFFull);
  bool hasknife = gbits != 0;
  int klane = g * 8 + (__ffs(gbits) - 1);  // valid only if hasknife
  bool is_kl = hasknife && (lane == klane);
  uint32_t kbit = (kc >= 0) ? (1u << (kc & 7)) : 0u;

  uint32_t ma_bits = is_kl ? (imask | kbit) : imask;
  uint64_t mA = gather_mask_bits(retrieve_bits(ma_bits, w, l), g);
  uint64_t m = mA;

  if (__any(hasknife)) {
    if (hasknife) {
      uint32_t mb_bits = is_kl ? (imask & ~kbit) : imask;
      uint64_t mB = gather_mask_bits(retrieve_bits(mb_bits, w, l), g);
      if (mA != mB) {
        int kp = __shfl(kpos ? 1 : 0, klane);
        m = kp ? mA : mB;
      }
    }
  }

  uint32_t byte = (uint32_t)((m >> (8 * l)) & 0xFFull);
  u32x4 o;
#pragma unroll
  for (int p = 0; p < 4; ++p) {
    uint32_t lo = ((byte >> (2 * p)) & 1u) ? 0x3F80u : 0u;
    uint32_t hi = ((byte >> (2 * p + 1)) & 1u) ? 0x3F800000u : 0u;
    o[p] = lo | hi;
  }
  *(u32x4*)(comb + (size_t)sid * 576 + 512 + l * 8) = o;
}

// ---------------------------------------------------------------- bf16 MFMA GEMM
// global_load_lds width-16 staging (R12, kept).
__global__ __launch_bounds__(256)
void k_gemm_bf16(const uint16_t* __restrict__ A, const uint16_t* __restrict__ BT,
                 const float* __restrict__ bias, uint16_t* __restrict__ C,
                 int M, int N, int K, int relu) {
  constexpr int BM = 128, BN = 128, BK = 32;
  __shared__ __align__(16) uint16_t As[BM][BK];
  __shared__ __align__(16) uint16_t Bs[BN][BK];
  const int t = threadIdx.x;
  const int lane = t & 63, wid = t >> 6;
  const int wr = wid >> 1, wc = wid & 1;
  const int bm = blockIdx.y * BM, bn = blockIdx.x * BN;

  f32x4 acc[4][4] = {};

  const int l15 = lane & 15, kb = (lane >> 4) * 8;
  const int i0 = t, i1 = t + 256;
  const int r0 = i0 >> 2, c0 = (i0 & 3) * 8;
  const int r1 = i1 >> 2, c1 = (i1 & 3) * 8;
  const uint16_t* A0 = A + (size_t)(bm + r0) * K + c0;
  const uint16_t* A1 = A + (size_t)(bm + r1) * K + c1;
  const uint16_t* B0 = BT + (size_t)(bn + r0) * K + c0;
  const uint16_t* B1 = BT + (size_t)(bn + r1) * K + c1;
  uint16_t* Al = &As[0][0];
  uint16_t* Bl = &Bs[0][0];

  for (int kt = 0; kt < K / BK; ++kt) {
    __syncthreads();
    const int ko = kt * BK;
    gload16(A0 + ko, Al + i0 * 8);
    gload16(A1 + ko, Al + i1 * 8);
    gload16(B0 + ko, Bl + i0 * 8);
    gload16(B1 + ko, Bl + i1 * 8);
    __syncthreads();
    bf16x8 af[4], bf[4];
#pragma unroll
    for (int m = 0; m < 4; ++m)
      af[m] = *(const bf16x8*)&As[wr * 64 + m * 16 + l15][kb];
#pragma unroll
    for (int n = 0; n < 4; ++n)
      bf[n] = *(const bf16x8*)&Bs[wc * 64 + n * 16 + l15][kb];
#pragma unroll
    for (int m = 0; m < 4; ++m)
#pragma unroll
      for (int n = 0; n < 4; ++n)
        acc[m][n] = __builtin_amdgcn_mfma_f32_16x16x32_bf16(af[m], bf[n],
                                                            acc[m][n], 0, 0, 0);
  }
#pragma unroll
  for (int m = 0; m < 4; ++m) {
    int row = bm + wr * 64 + m * 16 + (lane >> 4) * 4;
#pragma unroll
    for (int n = 0; n < 4; ++n) {
      int col = bn + wc * 64 + n * 16 + l15;
      float bsv = bias[col];
#pragma unroll
      for (int r = 0; r < 4; ++r) {
        float v = acc[m][n][r] + bsv;
        if (relu) v = fmaxf(v, 0.f);
        C[(size_t)(row + r) * N + col] = f2bf(v);
      }
    }
  }
}

// ---------------------------------------------------------------- n3 (N=2)
__global__ __launch_bounds__(256) void k_n3(const uint16_t* __restrict__ h2,
                                            const uint16_t* __restrict__ w3,
                                            const float* __restrict__ b3,
                                            float* __restrict__ out, int M) {
  const int lane = threadIdx.x & 63;
  const int wglob = (blockIdx.x * 256 + threadIdx.x) >> 6;
  const int nw = (gridDim.x * 256) >> 6;
  u16x8 wa = *(const u16x8*)(w3 + lane * 16);
  u16x8 wb = *(const u16x8*)(w3 + lane * 16 + 8);
  u16x8 wc = *(const u16x8*)(w3 + 1024 + lane * 16);
  u16x8 wd = *(const u16x8*)(w3 + 1024 + lane * 16 + 8);
  const float b0 = b3[0], b1 = b3[1];
  for (int row = wglob; row < M; row += nw) {
    const uint16_t* hr = h2 + (size_t)row * 1024;
    u16x8 h0 = *(const u16x8*)(hr + lane * 8);
    u16x8 h1 = *(const u16x8*)(hr + 512 + lane * 8);
    float a0 = 0.f, a1 = 0.f;
#pragma unroll
    for (int e = 0; e < 4; ++e) {
      float h = bf2f(h0[e]);
      a0 = fmaf(h, bf2f(wa[2 * e]), a0);
      a1 = fmaf(h, bf2f(wa[2 * e + 1]), a1);
    }
#pragma unroll
    for (int e = 4; e < 8; ++e) {
      float h = bf2f(h0[e]);
      a0 = fmaf(h, bf2f(wb[2 * e - 8]), a0);
      a1 = fmaf(h, bf2f(wb[2 * e - 7]), a1);
    }
#pragma unroll
    for (int e = 0; e < 4; ++e) {
      float h = bf2f(h1[e]);
      a0 = fmaf(h, bf2f(wc[2 * e]), a0);
      a1 = fmaf(h, bf2f(wc[2 * e + 1]), a1);
    }
#pragma unroll
    for (int e = 4; e < 8; ++e) {
      float h = bf2f(h1[e]);
      a0 = fmaf(h, bf2f(wd[2 * e - 8]), a0);
      a1 = fmaf(h, bf2f(wd[2 * e - 7]), a1);
    }
#pragma unroll
    for (int off = 32; off; off >>= 1) {
      a0 += __shfl_xor(a0, off, 64);
      a1 += __shfl_xor(a1, off, 64);
    }
    if (lane == 0) {
      out[(size_t)row * 2 + 0] = a0 + b0;
      out[(size_t)row * 2 + 1] = a1 + b1;
    }
  }
}

// ---------------------------------------------------------------- launch
extern "C" void kernel_launch(void* const* d_in, const int* in_sizes, int n_in,
                              void* d_out, int out_size, void* d_ws, size_t ws_size,
                              hipStream_t stream) {
  const float* x     = (const float*)d_in[0];
  const float* e_w1  = (const float*)d_in[1];
  const float* e_b1  = (const float*)d_in[2];
  const float* e_w2  = (const float*)d_in[3];
  const float* e_b2  = (const float*)d_in[4];
  const float* hop_w = (const float*)d_in[5];
  const float* n_w1  = (const float*)d_in[6];
  const float* n_b1  = (const float*)d_in[7];
  const float* n_w2  = (const float*)d_in[8];
  const float* n_b2  = (const float*)d_in[9];
  const float* n_w3  = (const float*)d_in[10];
  const float* n_b3  = (const float*)d_in[11];
  float* out = (float*)d_out;
  char* ws = (char*)d_ws;

  float*    h1e  = (float*)(ws + 0);              // 32768x1024 f32 (phase A)
  uint16_t* h1   = (uint16_t*)(ws + 0);           // 32768x1024 bf16 (phase C)
  uint16_t* h2   = (uint16_t*)(ws + 67108864);
  uint16_t* comb = (uint16_t*)(ws + 134217728);
  float*    enc  = (float*)(ws + 171966464);
  uint16_t* w1t  = (uint16_t*)(ws + 180355072);
  uint16_t* w2t  = (uint16_t*)(ws + 181534720);
  uint16_t* w3b  = (uint16_t*)(ws + 183631872);

  k_conv_x<<<8192, 256, 0, stream>>>(x, comb);
  k_convT<<<dim3(1024 / 64, 576 / 64), 256, 0, stream>>>(n_w1, w1t, 576, 1024);
  k_convT<<<dim3(1024 / 64, 1024 / 64), 256, 0, stream>>>(n_w2, w2t, 1024, 1024);
  k_conv<<<(2048 + 255) / 256, 256, 0, stream>>>(n_w3, w3b, 2048);

  // encoder — f32 OpenBLAS replica, K-tile 32, 4 blocks/CU
  k_enc<512, true><<<dim3(1024 / 64, 32768 / 128), 256, 0, stream>>>(
      x, e_w1, e_b1, h1e, 1024);
  k_enc<1024, false><<<dim3(1, 32768 / 128), 256, 0, stream>>>(
      h1e, e_w2, e_b2, enc, 64);

  // hopfield — bitmask state, runtime loops (no spill)
  k_hopfield<<<32768 / 32, 256, 0, stream>>>(enc, hop_w, comb);

  // Q-network (bf16 MFMA, global_load_lds staging)
  k_gemm_bf16<<<dim3(1024 / 128, 32768 / 128), 256, 0, stream>>>(
      comb, w1t, n_b1, h1, 32768, 1024, 576, 1);
  k_gemm_bf16<<<dim3(1024 / 128, 32768 / 128), 256, 0, stream>>>(
      h1, w2t, n_b2, h2, 32768, 1024, 1024, 1);
  k_n3<<<512, 256, 0, stream>>>(h2, w3b, n_b3, out, 32768);
}